// Round 5
// baseline (480.651 us; speedup 1.0000x reference)
//
#include <hip/hip_runtime.h>
#include <hip/hip_bf16.h>
#include <math.h>

// Problem constants (B=1)
#define S_LEN 2048
#define HDIM  4096
#define NQ_H  32
#define NKV_H 8
#define HD_   128
#define DQ (NQ_H*HD_)   // 4096
#define DKV (NKV_H*HD_) // 1024
#define NFUSE (DQ + 2*DKV)  // 6144

typedef unsigned short u16;
typedef unsigned int   u32;
typedef __attribute__((ext_vector_type(8))) short short8;   // 8 bf16 = 4 VGPRs
typedef __attribute__((ext_vector_type(4))) float f32x4;

__device__ __forceinline__ u16 bf16_rne(float x) {
    u32 u = __float_as_uint(x);
    u = (u + 0x7FFFu + ((u >> 16) & 1u)) >> 16;
    return (u16)u;
}
__device__ __forceinline__ float bf16_to_f(u16 h) {
    return __uint_as_float(((u32)h) << 16);
}
__device__ __forceinline__ void glds16(const u16* g, u16* l) {
    __builtin_amdgcn_global_load_lds(
        (const __attribute__((address_space(1))) u32*)g,
        (__attribute__((address_space(3))) u32*)l,
        16, 0, 0);
}

// ---------------------------------------------------------------------------
// Merged conversions: blocks [0,4096) cvt X -> Xb bf16; blocks [4096, 4096+24576)
// transpose+convert [wq|wk|wv] -> WT (6144 x 4096 bf16). One dispatch, BW overlap.
// ---------------------------------------------------------------------------
__global__ __launch_bounds__(256) void cvt_all(const float* __restrict__ X,
                                               u16* __restrict__ Xb,
                                               const float* __restrict__ wq,
                                               const float* __restrict__ wk,
                                               const float* __restrict__ wv,
                                               u16* __restrict__ WT) {
    __shared__ float tile[32][33];
    const int bid = blockIdx.x;
    if (bid < 4096) {
        int i = (bid * 256 + threadIdx.x) * 8;
        float4 a = *(const float4*)&X[i];
        float4 b = *(const float4*)&X[i + 4];
        u16 h[8];
        h[0] = bf16_rne(a.x); h[1] = bf16_rne(a.y); h[2] = bf16_rne(a.z); h[3] = bf16_rne(a.w);
        h[4] = bf16_rne(b.x); h[5] = bf16_rne(b.y); h[6] = bf16_rne(b.z); h[7] = bf16_rne(b.w);
        *(uint4*)&Xb[i] = *(uint4*)h;
        return;
    }
    const int wid = bid - 4096;
    const int n0g = (wid % 192) * 32;   // output row base (0..6112)
    const int k0  = (wid / 192) * 32;
    const float* W; int Nsrc, nloc0;
    if (n0g < DQ)            { W = wq; Nsrc = DQ;  nloc0 = n0g; }
    else if (n0g < DQ + DKV) { W = wk; Nsrc = DKV; nloc0 = n0g - DQ; }
    else                     { W = wv; Nsrc = DKV; nloc0 = n0g - DQ - DKV; }
    const int tx = threadIdx.x & 31;
    const int ty = threadIdx.x >> 5;   // 0..7
#pragma unroll
    for (int i = 0; i < 4; ++i)
        tile[ty + 8 * i][tx] = W[(size_t)(k0 + ty + 8 * i) * Nsrc + nloc0 + tx];
    __syncthreads();
#pragma unroll
    for (int i = 0; i < 4; ++i) {
        int r = ty + 8 * i;
        WT[(size_t)(n0g + r) * HDIM + k0 + tx] = bf16_rne(tile[tx][r]);
    }
}

// ---------------------------------------------------------------------------
// Fused QKV GEMM, 256x256 tile, BK=64, 8-phase schedule (T2+T3+T4+T5).
// Grid = 256 blocks: 0..191 GEMM tiles (24 n x 8 m), 192..255 filler blocks
// that transpose wo (4096x4096 fp32) -> woT (bf16) on otherwise-idle CUs.
// ---------------------------------------------------------------------------
#define AOFFU(par, mh) ((par) * 16384 + (mh) * 8192)
#define BOFFU(par, nh) (32768 + (par) * 16384 + (nh) * 8192)

__global__ __launch_bounds__(512, 2) void gemm_qkv256(const u16* __restrict__ A,
                                                      const u16* __restrict__ BT,
                                                      u16* __restrict__ qb,
                                                      u16* __restrict__ kb,
                                                      u16* __restrict__ vb,
                                                      const float* __restrict__ wo,
                                                      u16* __restrict__ woT) {
    const int K  = HDIM;
    const int NT = K / 64;   // 64 K-tiles
    __shared__ u16 smem[65536] __attribute__((aligned(16)));

    const int id = blockIdx.x;
    const int t  = threadIdx.x;

    if (id >= 192) {
        // ---- filler: wo (DQ x HDIM fp32) -> woT[n*DQ+k] bf16, 64-col strip ----
        // LDS fp32 tile stride 65 (odd): 2-way max bank aliasing (free).
        const int b  = id - 192;        // 0..63
        const int n0 = b * 64;          // woT row band
        float* tile = (float*)smem;     // [64][65] fp32
        const int r  = t >> 3;          // 0..63
        const int c8 = (t & 7) * 8;     // 0..56
        for (int k0 = 0; k0 < DQ; k0 += 64) {
            float4 x0 = *(const float4*)&wo[(size_t)(k0 + r) * HDIM + n0 + c8];
            float4 x1 = *(const float4*)&wo[(size_t)(k0 + r) * HDIM + n0 + c8 + 4];
            float* tr = &tile[r * 65 + c8];
            tr[0] = x0.x; tr[1] = x0.y; tr[2] = x0.z; tr[3] = x0.w;
            tr[4] = x1.x; tr[5] = x1.y; tr[6] = x1.z; tr[7] = x1.w;
            __syncthreads();
            u16 h[8];
#pragma unroll
            for (int j = 0; j < 8; ++j) h[j] = bf16_rne(tile[(c8 + j) * 65 + r]);
            *(uint4*)&woT[(size_t)(n0 + r) * DQ + k0 + c8] = *(uint4*)h;
            __syncthreads();
        }
        return;
    }

    const int w    = t >> 6;        // 0..7
    const int lane = t & 63;
    const int wm   = w >> 2;        // 0..1
    const int wn   = w & 3;         // 0..3
    const int fr   = lane & 15;
    const int quad = lane >> 4;
    const int m0   = (id / 24) * 256;
    const int n0   = (id % 24) * 256;

    // ---- staging geometry: linear LDS dest, inverse-swizzled global source ----
    const int lrow = lane >> 3;               // row within 8-row group
    const int lc   = (lane & 7) ^ lrow;       // logical chunk for this lane's slot
    const u16* const baseA = A  + (size_t)(m0 + w * 16 + lrow) * K + lc * 8;
    const u16* const baseB = BT + (size_t)(n0 + w * 16 + lrow) * K + lc * 8;
    const int wdst = w * 1024;                // wave's 2KB (u16 units) in a half

    // ---- ds_read geometry (swizzled chunks) ----
    const int pc0  = (quad ^ (fr & 7)) * 8;
    const int pc1  = pc0 ^ 32;                // (chunk^4)*8
    const int aRow = (wm * 64 + fr) * 64;
    const int bRow = (wn * 32 + fr) * 64;

    f32x4 acc[2][2][4][2];
#pragma unroll
    for (int a = 0; a < 2; ++a)
#pragma unroll
        for (int b = 0; b < 2; ++b)
#pragma unroll
            for (int c = 0; c < 4; ++c)
#pragma unroll
                for (int d = 0; d < 2; ++d) acc[a][b][c][d] = (f32x4)0.f;

    short8 ar0[4][2], ar1[4][2], br[2][2];

    auto stA = [&](int off, int tile, int mh) {
        const u16* g = baseA + (size_t)mh * 128 * K + tile * 64;
        glds16(g,                 smem + off + wdst);
        glds16(g + (size_t)8 * K, smem + off + wdst + 512);
    };
    auto stB = [&](int off, int tile, int nh) {
        const u16* g = baseB + (size_t)nh * 128 * K + tile * 64;
        glds16(g,                 smem + off + wdst);
        glds16(g + (size_t)8 * K, smem + off + wdst + 512);
    };
    auto rdA = [&](short8 (&d)[4][2], int off) {
#pragma unroll
        for (int mr = 0; mr < 4; ++mr) {
            d[mr][0] = *(const short8*)&smem[off + aRow + mr * 1024 + pc0];
            d[mr][1] = *(const short8*)&smem[off + aRow + mr * 1024 + pc1];
        }
    };
    auto rdB = [&](short8 (&d)[2][2], int off) {
#pragma unroll
        for (int nc = 0; nc < 2; ++nc) {
            d[nc][0] = *(const short8*)&smem[off + bRow + nc * 1024 + pc0];
            d[nc][1] = *(const short8*)&smem[off + bRow + nc * 1024 + pc1];
        }
    };
    auto mma = [&](short8 (&a)[4][2], short8 (&b)[2][2], f32x4 (&c)[4][2]) {
        __builtin_amdgcn_s_setprio(1);
#pragma unroll
        for (int mr = 0; mr < 4; ++mr)
#pragma unroll
            for (int nc = 0; nc < 2; ++nc) {
                c[mr][nc] = __builtin_amdgcn_mfma_f32_16x16x32_bf16(a[mr][0], b[nc][0], c[mr][nc], 0, 0, 0);
                c[mr][nc] = __builtin_amdgcn_mfma_f32_16x16x32_bf16(a[mr][1], b[nc][1], c[mr][nc], 0, 0, 0);
            }
        __builtin_amdgcn_s_setprio(0);
    };

    // ---- prologue: tile0 fully + tile1 {A0,B0,A1}; B1(t1) comes in phase 1 ----
    stA(AOFFU(0,0), 0, 0);
    stB(BOFFU(0,0), 0, 0);
    stA(AOFFU(0,1), 0, 1);
    stB(BOFFU(0,1), 0, 1);
    stA(AOFFU(1,0), 1, 0);
    stB(BOFFU(1,0), 1, 0);
    stA(AOFFU(1,1), 1, 1);
    asm volatile("s_waitcnt vmcnt(6)" ::: "memory");   // tile0 landed
    __builtin_amdgcn_s_barrier();

    for (int T = 0; T < NT; T += 2) {
        const int ts2 = (T + 2 < NT) ? T + 2 : NT - 1;   // clamped (dead-slot writes)
        const int ts3 = (T + 3 < NT) ? T + 3 : NT - 1;
        // ---- phase 1: quad (0,0) of tile T (par0); stage S(T+1,B1) ----
        rdA(ar0, AOFFU(0,0));
        rdB(br,  BOFFU(0,0));
        stB(BOFFU(1,1), T + 1, 1);
        __builtin_amdgcn_s_barrier();
        asm volatile("s_waitcnt lgkmcnt(0)" ::: "memory");
        mma(ar0, br, acc[0][0]);
        __builtin_amdgcn_s_barrier();
        // ---- phase 2: (1,0); stage S(T+2,A0) ----
        rdA(ar1, AOFFU(0,1));
        stA(AOFFU(0,0), ts2, 0);
        __builtin_amdgcn_s_barrier();
        asm volatile("s_waitcnt lgkmcnt(0)" ::: "memory");
        mma(ar1, br, acc[1][0]);
        __builtin_amdgcn_s_barrier();
        // ---- phase 3: (1,1); stage S(T+2,B0) ----
        rdB(br, BOFFU(0,1));
        stB(BOFFU(0,0), ts2, 0);
        __builtin_amdgcn_s_barrier();
        asm volatile("s_waitcnt lgkmcnt(0)" ::: "memory");
        mma(ar1, br, acc[1][1]);
        __builtin_amdgcn_s_barrier();
        // ---- phase 4: (0,1) (regs only); stage S(T+2,A1); vmcnt(6) -> T+1 ready ----
        stA(AOFFU(0,1), ts2, 1);
        __builtin_amdgcn_s_barrier();
        asm volatile("s_waitcnt lgkmcnt(0)" ::: "memory");
        mma(ar0, br, acc[0][1]);
        asm volatile("s_waitcnt vmcnt(6)" ::: "memory");
        __builtin_amdgcn_s_barrier();
        // ---- phase 5: (0,0) of tile T+1 (par1); stage S(T+2,B1) ----
        rdA(ar0, AOFFU(1,0));
        rdB(br,  BOFFU(1,0));
        stB(BOFFU(0,1), ts2, 1);
        __builtin_amdgcn_s_barrier();
        asm volatile("s_waitcnt lgkmcnt(0)" ::: "memory");
        mma(ar0, br, acc[0][0]);
        __builtin_amdgcn_s_barrier();
        // ---- phase 6: (1,0); stage S(T+3,A0) ----
        rdA(ar1, AOFFU(1,1));
        stA(AOFFU(1,0), ts3, 0);
        __builtin_amdgcn_s_barrier();
        asm volatile("s_waitcnt lgkmcnt(0)" ::: "memory");
        mma(ar1, br, acc[1][0]);
        __builtin_amdgcn_s_barrier();
        // ---- phase 7: (1,1); stage S(T+3,B0) ----
        rdB(br, BOFFU(1,1));
        stB(BOFFU(1,0), ts3, 0);
        __builtin_amdgcn_s_barrier();
        asm volatile("s_waitcnt lgkmcnt(0)" ::: "memory");
        mma(ar1, br, acc[1][1]);
        __builtin_amdgcn_s_barrier();
        // ---- phase 8: (0,1) (regs only); stage S(T+3,A1); vmcnt(6) -> T+2 ready ----
        stA(AOFFU(1,1), ts3, 1);
        __builtin_amdgcn_s_barrier();
        asm volatile("s_waitcnt lgkmcnt(0)" ::: "memory");
        mma(ar0, br, acc[0][1]);
        asm volatile("s_waitcnt vmcnt(6)" ::: "memory");
        __builtin_amdgcn_s_barrier();
    }

    // ---- epilogue: region select + C write (bf16) ----
    u16* dst; int stride, nbase;
    if (n0 < DQ)            { dst = qb; stride = DQ;  nbase = n0; }
    else if (n0 < DQ + DKV) { dst = kb; stride = DKV; nbase = n0 - DQ; }
    else                    { dst = vb; stride = DKV; nbase = n0 - DQ - DKV; }

    const int col = lane & 15;
    const int rq  = (lane >> 4) * 4;
#pragma unroll
    for (int mh = 0; mh < 2; ++mh)
#pragma unroll
        for (int nh = 0; nh < 2; ++nh)
#pragma unroll
            for (int mr = 0; mr < 4; ++mr)
#pragma unroll
                for (int nc = 0; nc < 2; ++nc)
#pragma unroll
                    for (int i = 0; i < 4; ++i)
                        dst[(size_t)(m0 + mh * 128 + wm * 64 + mr * 16 + rq + i) * stride
                            + nbase + nh * 128 + wn * 32 + nc * 16 + col] =
                            bf16_rne(acc[mh][nh][mr][nc][i]);
}

// ---------------------------------------------------------------------------
// O-projection GEMM, 256x256 tile, 8-phase, split-K=2 with FUSED serial
// reduction: z=0 stores partial to C, release-flags; z=1 acquire-spins,
// then C += acc. Grid 256 blocks = 1/CU (all co-resident; z=0 dispatch first).
// ---------------------------------------------------------------------------
__global__ __launch_bounds__(512, 2) void gemm_out256(const u16* __restrict__ A,
                                                      const u16* __restrict__ BT,
                                                      float* __restrict__ C,
                                                      u32* __restrict__ flags) {
    const int LDA = DQ;      // row stride of A and BT (both K-major, K total = 4096)
    const int NT  = 32;      // K-half = 2048 -> 32 K-tiles of 64
    __shared__ u16 smem[65536] __attribute__((aligned(16)));

    const int t    = threadIdx.x;
    const int w    = t >> 6;
    const int lane = t & 63;
    const int wm   = w >> 2;
    const int wn   = w & 3;
    const int fr   = lane & 15;
    const int quad = lane >> 4;
    const int m0   = blockIdx.y * 256;
    const int n0   = blockIdx.x * 256;
    const int kz   = blockIdx.z * 2048;   // K-half base
    const int tile_id = blockIdx.y * 16 + blockIdx.x;

    const int lrow = lane >> 3;
    const int lc   = (lane & 7) ^ lrow;
    const u16* const baseA = A  + (size_t)(m0 + w * 16 + lrow) * LDA + kz + lc * 8;
    const u16* const baseB = BT + (size_t)(n0 + w * 16 + lrow) * LDA + kz + lc * 8;
    const int wdst = w * 1024;

    const int pc0  = (quad ^ (fr & 7)) * 8;
    const int pc1  = pc0 ^ 32;
    const int aRow = (wm * 64 + fr) * 64;
    const int bRow = (wn * 32 + fr) * 64;

    f32x4 acc[2][2][4][2];
#pragma unroll
    for (int a = 0; a < 2; ++a)
#pragma unroll
        for (int b = 0; b < 2; ++b)
#pragma unroll
            for (int c = 0; c < 4; ++c)
#pragma unroll
                for (int d = 0; d < 2; ++d) acc[a][b][c][d] = (f32x4)0.f;

    short8 ar0[4][2], ar1[4][2], br[2][2];

    auto stA = [&](int off, int tile, int mh) {
        const u16* g = baseA + (size_t)mh * 128 * LDA + tile * 64;
        glds16(g,                   smem + off + wdst);
        glds16(g + (size_t)8 * LDA, smem + off + wdst + 512);
    };
    auto stB = [&](int off, int tile, int nh) {
        const u16* g = baseB + (size_t)nh * 128 * LDA + tile * 64;
        glds16(g,                   smem + off + wdst);
        glds16(g + (size_t)8 * LDA, smem + off + wdst + 512);
    };
    auto rdA = [&](short8 (&d)[4][2], int off) {
#pragma unroll
        for (int mr = 0; mr < 4; ++mr) {
            d[mr][0] = *(const short8*)&smem[off + aRow + mr * 1024 + pc0];
            d[mr][1] = *(const short8*)&smem[off + aRow + mr * 1024 + pc1];
        }
    };
    auto rdB = [&](short8 (&d)[2][2], int off) {
#pragma unroll
        for (int nc = 0; nc < 2; ++nc) {
            d[nc][0] = *(const short8*)&smem[off + bRow + nc * 1024 + pc0];
            d[nc][1] = *(const short8*)&smem[off + bRow + nc * 1024 + pc1];
        }
    };
    auto mma = [&](short8 (&a)[4][2], short8 (&b)[2][2], f32x4 (&c)[4][2]) {
        __builtin_amdgcn_s_setprio(1);
#pragma unroll
        for (int mr = 0; mr < 4; ++mr)
#pragma unroll
            for (int nc = 0; nc < 2; ++nc) {
                c[mr][nc] = __builtin_amdgcn_mfma_f32_16x16x32_bf16(a[mr][0], b[nc][0], c[mr][nc], 0, 0, 0);
                c[mr][nc] = __builtin_amdgcn_mfma_f32_16x16x32_bf16(a[mr][1], b[nc][1], c[mr][nc], 0, 0, 0);
            }
        __builtin_amdgcn_s_setprio(0);
    };

    stA(AOFFU(0,0), 0, 0);
    stB(BOFFU(0,0), 0, 0);
    stA(AOFFU(0,1), 0, 1);
    stB(BOFFU(0,1), 0, 1);
    stA(AOFFU(1,0), 1, 0);
    stB(BOFFU(1,0), 1, 0);
    stA(AOFFU(1,1), 1, 1);
    asm volatile("s_waitcnt vmcnt(6)" ::: "memory");
    __builtin_amdgcn_s_barrier();

    for (int T = 0; T < NT; T += 2) {
        const int ts2 = (T + 2 < NT) ? T + 2 : NT - 1;
        const int ts3 = (T + 3 < NT) ? T + 3 : NT - 1;
        rdA(ar0, AOFFU(0,0));
        rdB(br,  BOFFU(0,0));
        stB(BOFFU(1,1), T + 1, 1);
        __builtin_amdgcn_s_barrier();
        asm volatile("s_waitcnt lgkmcnt(0)" ::: "memory");
        mma(ar0, br, acc[0][0]);
        __builtin_amdgcn_s_barrier();
        rdA(ar1, AOFFU(0,1));
        stA(AOFFU(0,0), ts2, 0);
        __builtin_amdgcn_s_barrier();
        asm volatile("s_waitcnt lgkmcnt(0)" ::: "memory");
        mma(ar1, br, acc[1][0]);
        __builtin_amdgcn_s_barrier();
        rdB(br, BOFFU(0,1));
        stB(BOFFU(0,0), ts2, 0);
        __builtin_amdgcn_s_barrier();
        asm volatile("s_waitcnt lgkmcnt(0)" ::: "memory");
        mma(ar1, br, acc[1][1]);
        __builtin_amdgcn_s_barrier();
        stA(AOFFU(0,1), ts2, 1);
        __builtin_amdgcn_s_barrier();
        asm volatile("s_waitcnt lgkmcnt(0)" ::: "memory");
        mma(ar0, br, acc[0][1]);
        asm volatile("s_waitcnt vmcnt(6)" ::: "memory");
        __builtin_amdgcn_s_barrier();
        rdA(ar0, AOFFU(1,0));
        rdB(br,  BOFFU(1,0));
        stB(BOFFU(0,1), ts2, 1);
        __builtin_amdgcn_s_barrier();
        asm volatile("s_waitcnt lgkmcnt(0)" ::: "memory");
        mma(ar0, br, acc[0][0]);
        __builtin_amdgcn_s_barrier();
        rdA(ar1, AOFFU(1,1));
        stA(AOFFU(1,0), ts3, 0);
        __builtin_amdgcn_s_barrier();
        asm volatile("s_waitcnt lgkmcnt(0)" ::: "memory");
        mma(ar1, br, acc[1][0]);
        __builtin_amdgcn_s_barrier();
        rdB(br, BOFFU(1,1));
        stB(BOFFU(1,0), ts3, 0);
        __builtin_amdgcn_s_barrier();
        asm volatile("s_waitcnt lgkmcnt(0)" ::: "memory");
        mma(ar1, br, acc[1][1]);
        __builtin_amdgcn_s_barrier();
        stA(AOFFU(1,1), ts3, 1);
        __builtin_amdgcn_s_barrier();
        asm volatile("s_waitcnt lgkmcnt(0)" ::: "memory");
        mma(ar0, br, acc[0][1]);
        asm volatile("s_waitcnt vmcnt(6)" ::: "memory");
        __builtin_amdgcn_s_barrier();
    }

    const int col = lane & 15;
    const int rq  = (lane >> 4) * 4;
    if (blockIdx.z == 0) {
        // store partial, then release-flag the tile
#pragma unroll
        for (int mh = 0; mh < 2; ++mh)
#pragma unroll
            for (int nh = 0; nh < 2; ++nh)
#pragma unroll
                for (int mr = 0; mr < 4; ++mr)
#pragma unroll
                    for (int nc = 0; nc < 2; ++nc)
#pragma unroll
                        for (int i = 0; i < 4; ++i)
                            C[(size_t)(m0 + mh * 128 + wm * 64 + mr * 16 + rq + i) * HDIM
                              + n0 + nh * 128 + wn * 32 + nc * 16 + col] =
                                acc[mh][nh][mr][nc][i];
        __syncthreads();   // drains vmcnt: all stores in L2
        if (t == 0)
            __hip_atomic_store(&flags[tile_id], 1u, __ATOMIC_RELEASE, __HIP_MEMORY_SCOPE_AGENT);
    } else {
        // acquire-spin for partner's partial, then C += acc
        if (t == 0) {
            while (__hip_atomic_load(&flags[tile_id], __ATOMIC_ACQUIRE, __HIP_MEMORY_SCOPE_AGENT) == 0u)
                __builtin_amdgcn_s_sleep(2);
        }
        __syncthreads();
#pragma unroll
        for (int mh = 0; mh < 2; ++mh)
#pragma unroll
            for (int nh = 0; nh < 2; ++nh)
#pragma unroll
                for (int mr = 0; mr < 4; ++mr)
#pragma unroll
                    for (int nc = 0; nc < 2; ++nc)
#pragma unroll
                        for (int i = 0; i < 4; ++i) {
                            size_t off = (size_t)(m0 + mh * 128 + wm * 64 + mr * 16 + rq + i) * HDIM
                                         + n0 + nh * 128 + wn * 32 + nc * 16 + col;
                            C[off] += acc[mh][nh][mr][nc][i];
                        }
    }
}

// ---------------------------------------------------------------------------
// Merged RoPE (blocks [0,5120)) + V transpose (blocks [5120, 5632)).
// ---------------------------------------------------------------------------
__global__ __launch_bounds__(256) void rope_tv(u16* __restrict__ q, u16* __restrict__ k,
                                               const float* __restrict__ cosT,
                                               const float* __restrict__ sinT,
                                               const u16* __restrict__ V,
                                               u16* __restrict__ Vt) {
    __shared__ u16 tile[64][72];
    const int bid = blockIdx.x;
    const int t = threadIdx.x;
    if (bid < 5120) {
        int idx = bid * 256 + t;                      // S * 40 * 16
        int d4   = (idx & 15) * 4;                    // 0..60
        int rest = idx >> 4;
        int head = rest % (NQ_H + NKV_H);
        int s    = rest / (NQ_H + NKV_H);
        u16* base = (head < NQ_H)
            ? q + ((size_t)s * NQ_H + head) * HD_
            : k + ((size_t)s * NKV_H + (head - NQ_H)) * HD_;
        float4 c  = *(const float4*)&cosT[s * HD_ + d4];
        float4 sn = *(const float4*)&sinT[s * HD_ + d4];
        u16 lo[4], hi[4];
        *(uint2*)lo = *(uint2*)&base[d4];
        *(uint2*)hi = *(uint2*)&base[d4 + 64];
        float cs[4] = {c.x, c.y, c.z, c.w};
        float ss[4] = {sn.x, sn.y, sn.z, sn.w};
        u16 nlo[4], nhi[4];
#pragma unroll
        for (int j = 0; j < 4; ++j) {
            float x1 = bf16_to_f(lo[j]);
            float x2 = bf16_to_f(hi[j]);
            nlo[j] = bf16_rne(x1 * cs[j] - x2 * ss[j]);
            nhi[j] = bf16_rne(x2 * cs[j] + x1 * ss[j]);
        }
        *(uint2*)&base[d4]      = *(uint2*)nlo;
        *(uint2*)&base[d4 + 64] = *(uint2*)nhi;
        return;
    }
    const int b   = bid - 5120;        // 0..511
    const int s0  = (b & 31) * 64;
    const int yy  = b >> 5;            // 0..15
    const int kvh = yy >> 1;
    const int d0  = (yy & 1) * 64;
    const int chunk = t & 7;       // 8 x 16B per 64-wide row
    const int row   = t >> 3;      // 0..31
#pragma unroll
    for (int p = 0; p < 2; ++p) {
        int s = row + 32 * p;
        uint4 x = *(const uint4*)&V[(size_t)(s0 + s) * DKV + kvh * HD_ + d0 + chunk * 8];
        *(uint4*)&tile[s][chunk * 8] = x;
    }
    __syncthreads();
#pragma unroll
    for (int p = 0; p < 2; ++p) {
        int d = row + 32 * p;
        u16 tmp[8];
#pragma unroll
        for (int j = 0; j < 8; ++j) tmp[j] = tile[chunk * 8 + j][d];
        *(uint4*)&Vt[(size_t)(kvh * HD_ + d0 + d) * S_LEN + s0 + chunk * 8] = *(uint4*)tmp;
    }
}

// ---------------------------------------------------------------------------
// MFMA flash attention, causal GQA, fixed-base softmax (exact after o/l).
// Block = (128 q-rows, head); 8 waves x 16 q-rows; KV tile 64.
// T14 reg-prefetch of next K/V tile; XOR-swizzled unpadded sK/sVt; T5 setprio.
// ---------------------------------------------------------------------------
#define QSTR 136
#define PSTR 76
__global__ __launch_bounds__(512, 4) void attn_mfma(const u16* __restrict__ Q,
                                                    const u16* __restrict__ K,
                                                    const u16* __restrict__ Vt,
                                                    u16* __restrict__ O) {
    __shared__ u16 smem[26112] __attribute__((aligned(16)));
    u16* sK  = smem;            // [64][128] swizzled : 8192 u16
    u16* sVt = smem + 8192;     // [128][64] swizzled : 8192 u16
    u16* sP  = smem + 16384;    // 8 x [16][PSTR]     : 9728 u16
    u16* sQ  = sVt;             // union (sQ only live pre-loop)

    const int id  = blockIdx.x;
    const int h   = id & 31;
    const int qt  = (id < 256) ? (15 - (id >> 5)) : ((id - 256) >> 5);
    const int kvh = h >> 2;
    const int q0  = qt * 128;
    const int t    = threadIdx.x;
    const int w    = t >> 6;        // 0..7
    const int lane = t & 63;
    const int fr   = lane & 15;
    const int quad = lane >> 4;
    const int nkt  = 2 * qt + 2;

    const float K1 = 0.12751744154f;   // (1/sqrt(128)) * log2(e)
    const float K2 = 11.5415603267f;   // 8 * log2(e)

    const int kRow  = t >> 3;                             // 0..63
    const int kC    = t & 7;                              // 2 chunks of 16B
    const int kLds0 = kRow * 128 + (((2 * kC + 0) ^ (kRow & 7)) * 8);
    const int kLds1 = kRow * 128 + (((2 * kC + 1) ^ (kRow & 7)) * 8);
    const u16* const kGp = K + (size_t)kRow * DKV + (size_t)kvh * HD_ + kC * 16;

    const int vRow  = t >> 2;                             // 0..127
    const int vC    = t & 3;
    const int vLds0 = vRow * 64 + (((2 * vC + 0) ^ (vRow & 7)) * 8);
    const int vLds1 = vRow * 64 + (((2 * vC + 1) ^ (vRow & 7)) * 8);
    const u16* const vGp = Vt + ((size_t)kvh * HD_ + vRow) * S_LEN + vC * 16;

    uint4 kr0 = *(const uint4*)(kGp);
    uint4 kr1 = *(const uint4*)(kGp + 8);
    uint4 vr0 = *(const uint4*)(vGp);
    uint4 vr1 = *(const uint4*)(vGp + 8);

    {
        const int col  = t & 15;
        const int row4 = t >> 4;    // 32 rows per pass
#pragma unroll
        for (int p = 0; p < 4; ++p) {
            int row = row4 + 32 * p;
            uint4 xv = *(const uint4*)&Q[(size_t)(q0 + row) * DQ + h * HD_ + col * 8];
            *(uint4*)&sQ[row * QSTR + col * 8] = xv;
        }
    }
    __syncthreads();

    short8 aq[4];
#pragma unroll
    for (int ks = 0; ks < 4; ++ks)
        aq[ks] = *(const short8*)&sQ[(16 * w + fr) * QSTR + ks * 32 + quad * 8];

    float lrow[4] = {0.f, 0.f, 0.f, 0.f};
    f32x4 oacc[8];
#pragma unroll
    for (int n8 = 0; n8 < 8; ++n8) oacc[n8] = (f32x4)0.f;

    u16* const sPw   = sP + w * (16 * PSTR);
    const int  qwTop = q0 + 16 * w;     // wave's first q row

    for (int kt = 0; kt < nkt; ++kt) {
        const int k0 = kt * 64;
        __syncthreads();

        *(uint4*)&sK[kLds0]  = kr0;
        *(uint4*)&sK[kLds1]  = kr1;
        *(uint4*)&sVt[vLds0] = vr0;
        *(uint4*)&sVt[vLds1] = vr1;
        if (kt + 1 < nkt) {
            const u16* kp = kGp + (size_t)(k0 + 64) * DKV;
            kr0 = *(const uint4*)(kp);
            kr1 = *(const uint4*)(kp + 8);
            const u16* vp = vGp + (k0 + 64);
            vr0 = *(const uint4*)(vp);
            vr1 = *(const uint4*)(vp + 8);
        }
        __syncthreads();

        if (k0 <= qwTop + 15) {
            f32x4 sacc[4];
#pragma unroll
            for (int nt = 0; nt < 4; ++nt) sacc[nt] = (f32x4)0.f;
            __builtin_amdgcn_s_setprio(1);
#pragma unroll
            for (int ks = 0; ks < 4; ++ks)
#pragma unroll
                for (int nt = 0; nt < 4; ++nt) {
                    const short8 bk = *(const short8*)
                        &sK[(nt * 16 + fr) * 128 + (((ks * 4 + quad) ^ (fr & 7)) * 8)];
                    sacc[nt] = __builtin_amdgcn_mfma_f32_16x16x32_bf16(aq[ks], bk, sacc[nt], 0, 0, 0);
                }
            __builtin_amdgcn_s_setprio(0);

            if (k0 + 63 > qwTop) {
#pragma unroll
                for (int nt = 0; nt < 4; ++nt) {
                    int key = k0 + nt * 16 + fr;
#pragma unroll
                    for (int i = 0; i < 4; ++i)
                        if (key > qwTop + quad * 4 + i) sacc[nt][i] = -INFINITY;
                }
            }

#pragma unroll
            for (int nt = 0; nt < 4; ++nt)
#pragma unroll
                for (int i = 0; i < 4; ++i) {
                    float p = __builtin_amdgcn_exp2f(fmaf(sacc[nt][i], K1, -K2));
                    lrow[i] += p;
                    sPw[(quad * 4 + i) * PSTR + nt * 16 + fr] = bf16_rne(p);
                }

            __builtin_amdgcn_s_setprio(1);
#pragma unroll
            for (int ks2 = 0; ks2 < 2; ++ks2) {
                const short8 ap = *(const short8*)&sPw[fr * PSTR + ks2 * 32 + quad * 8];
#pragma unroll
                for (int n8 = 0; n8 < 8; ++n8) {
                    const short8 bv = *(const short8*)
                        &sVt[(n8 * 16 + fr) * 64 + (((ks2 * 4 + quad) ^ (fr & 7)) * 8)];
                    oacc[n8] = __builtin_amdgcn_mfma_f32_16x16x32_bf16(ap, bv, oacc[n8], 0, 0, 0);
                }
            }
            __builtin_amdgcn_s_setprio(0);
        }
    }

#pragma unroll
    for (int i = 0; i < 4; ++i) {
        lrow[i] += __shfl_xor(lrow[i], 1);
        lrow[i] += __shfl_xor(lrow[i], 2);
        lrow[i] += __shfl_xor(lrow[i], 4);
        lrow[i] += __shfl_xor(lrow[i], 8);
    }
#pragma unroll
    for (int i = 0; i < 4; ++i) {
        float inv = 1.f / lrow[i];
        size_t base = (size_t)(qwTop + quad * 4 + i) * DQ + h * HD_;
#pragma unroll
        for (int n8 = 0; n8 < 8; ++n8)
            O[base + n8 * 16 + fr] = bf16_rne(oacc[n8][i] * inv);
    }
}

// ---------------------------------------------------------------------------
extern "C" void kernel_launch(void* const* d_in, const int* in_sizes, int n_in,
                              void* d_out, int out_size, void* d_ws, size_t ws_size,
                              hipStream_t stream) {
    const float* X    = (const float*)d_in[0];
    const float* cosT = (const float*)d_in[1];
    const float* sinT = (const float*)d_in[2];
    const float* wq   = (const float*)d_in[3];
    const float* wk   = (const float*)d_in[4];
    const float* wv   = (const float*)d_in[5];
    const float* wo   = (const float*)d_in[6];
    float* out = (float*)d_out;

    const size_t SDQ  = (size_t)S_LEN * DQ;    // 8.4M
    const size_t SDKV = (size_t)S_LEN * DKV;   // 2.1M
    const size_t WQKV = (size_t)HDIM * NFUSE;  // 25.2M

    // ws layout (u16), ~147 MB
    u16* Xb  = (u16*)d_ws;
    u16* qb  = Xb + SDQ;
    u16* kb  = qb + SDQ;
    u16* vb  = kb + SDKV;
    u16* vtb = vb + SDKV;
    u16* aob = vtb + SDKV;
    u16* WT  = aob + SDQ;      // fused qkv weights, 6144 x 4096
    u16* woT = WT + WQKV;

    // split-K tile flags reuse the (dead by then) Xb region
    u32* flags = (u32*)d_ws;

    dim3 blk(256);

    // merged conversions: X->Xb (4096 blocks) + [wq|wk|wv]->WT (24576 blocks)
    cvt_all<<<dim3(4096 + 24576), blk, 0, stream>>>(X, Xb, wq, wk, wv, WT);

    // fused QKV projection (192 GEMM blocks) + wo transpose on 64 filler blocks
    gemm_qkv256<<<dim3(256), dim3(512), 0, stream>>>(Xb, WT, qb, kb, vb, wo, woT);

    // merged rope (5120 blocks) + V pre-transpose (512 blocks)
    rope_tv<<<dim3(5120 + 512), blk, 0, stream>>>(qb, kb, cosT, sinT, vb, vtb);

    // attention: 512 blocks (16 q-tiles x 32 heads), 512 threads
    attn_mfma<<<dim3(512), dim3(512), 0, stream>>>(qb, kb, vtb, aob);

    // output projection: split-K=2, fused serial reduction via tile flags
    hipMemsetAsync(flags, 0, 128 * sizeof(u32), stream);
    gemm_out256<<<dim3(HDIM / 256, S_LEN / 256, 2), dim3(512), 0, stream>>>(aob, woT, out, flags);
}

// Round 6
// 434.004 us; speedup vs baseline: 1.1075x; 1.1075x over previous
//
#include <hip/hip_runtime.h>
#include <hip/hip_bf16.h>
#include <math.h>

// Problem constants (B=1)
#define S_LEN 2048
#define HDIM  4096
#define NQ_H  32
#define NKV_H 8
#define HD_   128
#define DQ (NQ_H*HD_)   // 4096
#define DKV (NKV_H*HD_) // 1024
#define NFUSE (DQ + 2*DKV)  // 6144

typedef unsigned short u16;
typedef unsigned int   u32;
typedef __attribute__((ext_vector_type(8))) short short8;   // 8 bf16 = 4 VGPRs
typedef __attribute__((ext_vector_type(4))) float f32x4;

__device__ __forceinline__ u16 bf16_rne(float x) {
    u32 u = __float_as_uint(x);
    u = (u + 0x7FFFu + ((u >> 16) & 1u)) >> 16;
    return (u16)u;
}
__device__ __forceinline__ float bf16_to_f(u16 h) {
    return __uint_as_float(((u32)h) << 16);
}
__device__ __forceinline__ void glds16(const u16* g, u16* l) {
    __builtin_amdgcn_global_load_lds(
        (const __attribute__((address_space(1))) u32*)g,
        (__attribute__((address_space(3))) u32*)l,
        16, 0, 0);
}

// ---------------------------------------------------------------------------
// Merged conversions: blocks [0,4096) cvt X -> Xb bf16; blocks [4096, 4096+24576)
// transpose+convert [wq|wk|wv] -> WT (6144 x 4096 bf16). One dispatch, BW overlap.
// ---------------------------------------------------------------------------
__global__ __launch_bounds__(256) void cvt_all(const float* __restrict__ X,
                                               u16* __restrict__ Xb,
                                               const float* __restrict__ wq,
                                               const float* __restrict__ wk,
                                               const float* __restrict__ wv,
                                               u16* __restrict__ WT) {
    __shared__ float tile[32][33];
    const int bid = blockIdx.x;
    if (bid < 4096) {
        int i = (bid * 256 + threadIdx.x) * 8;
        float4 a = *(const float4*)&X[i];
        float4 b = *(const float4*)&X[i + 4];
        u16 h[8];
        h[0] = bf16_rne(a.x); h[1] = bf16_rne(a.y); h[2] = bf16_rne(a.z); h[3] = bf16_rne(a.w);
        h[4] = bf16_rne(b.x); h[5] = bf16_rne(b.y); h[6] = bf16_rne(b.z); h[7] = bf16_rne(b.w);
        *(uint4*)&Xb[i] = *(uint4*)h;
        return;
    }
    const int wid = bid - 4096;
    const int n0g = (wid % 192) * 32;   // output row base (0..6112)
    const int k0  = (wid / 192) * 32;
    const float* W; int Nsrc, nloc0;
    if (n0g < DQ)            { W = wq; Nsrc = DQ;  nloc0 = n0g; }
    else if (n0g < DQ + DKV) { W = wk; Nsrc = DKV; nloc0 = n0g - DQ; }
    else                     { W = wv; Nsrc = DKV; nloc0 = n0g - DQ - DKV; }
    const int tx = threadIdx.x & 31;
    const int ty = threadIdx.x >> 5;   // 0..7
#pragma unroll
    for (int i = 0; i < 4; ++i)
        tile[ty + 8 * i][tx] = W[(size_t)(k0 + ty + 8 * i) * Nsrc + nloc0 + tx];
    __syncthreads();
#pragma unroll
    for (int i = 0; i < 4; ++i) {
        int r = ty + 8 * i;
        WT[(size_t)(n0g + r) * HDIM + k0 + tx] = bf16_rne(tile[tx][r]);
    }
}

// ---------------------------------------------------------------------------
// Fused QKV GEMM, 256x256 tile, BK=64, 8-phase schedule (T2+T3+T4+T5).
// Grid = 256 blocks: 0..191 GEMM tiles (24 n x 8 m), 192..255 filler blocks
// that transpose wo (4096x4096 fp32) -> woT (bf16) on otherwise-idle CUs.
// ---------------------------------------------------------------------------
#define AOFFU(par, mh) ((par) * 16384 + (mh) * 8192)
#define BOFFU(par, nh) (32768 + (par) * 16384 + (nh) * 8192)

__global__ __launch_bounds__(512, 2) void gemm_qkv256(const u16* __restrict__ A,
                                                      const u16* __restrict__ BT,
                                                      u16* __restrict__ qb,
                                                      u16* __restrict__ kb,
                                                      u16* __restrict__ vb,
                                                      const float* __restrict__ wo,
                                                      u16* __restrict__ woT) {
    const int K  = HDIM;
    const int NT = K / 64;   // 64 K-tiles
    __shared__ u16 smem[65536] __attribute__((aligned(16)));

    const int id = blockIdx.x;
    const int t  = threadIdx.x;

    if (id >= 192) {
        // ---- filler: wo (DQ x HDIM fp32) -> woT[n*DQ+k] bf16, 64-col strip ----
        // LDS fp32 tile stride 65 (odd): 2-way max bank aliasing (free).
        const int b  = id - 192;        // 0..63
        const int n0 = b * 64;          // woT row band
        float* tile = (float*)smem;     // [64][65] fp32
        const int r  = t >> 3;          // 0..63
        const int c8 = (t & 7) * 8;     // 0..56
        for (int k0 = 0; k0 < DQ; k0 += 64) {
            float4 x0 = *(const float4*)&wo[(size_t)(k0 + r) * HDIM + n0 + c8];
            float4 x1 = *(const float4*)&wo[(size_t)(k0 + r) * HDIM + n0 + c8 + 4];
            float* tr = &tile[r * 65 + c8];
            tr[0] = x0.x; tr[1] = x0.y; tr[2] = x0.z; tr[3] = x0.w;
            tr[4] = x1.x; tr[5] = x1.y; tr[6] = x1.z; tr[7] = x1.w;
            __syncthreads();
            u16 h[8];
#pragma unroll
            for (int j = 0; j < 8; ++j) h[j] = bf16_rne(tile[(c8 + j) * 65 + r]);
            *(uint4*)&woT[(size_t)(n0 + r) * DQ + k0 + c8] = *(uint4*)h;
            __syncthreads();
        }
        return;
    }

    const int w    = t >> 6;        // 0..7
    const int lane = t & 63;
    const int wm   = w >> 2;        // 0..1
    const int wn   = w & 3;         // 0..3
    const int fr   = lane & 15;
    const int quad = lane >> 4;
    const int m0   = (id / 24) * 256;
    const int n0   = (id % 24) * 256;

    // ---- staging geometry: linear LDS dest, inverse-swizzled global source ----
    const int lrow = lane >> 3;               // row within 8-row group
    const int lc   = (lane & 7) ^ lrow;       // logical chunk for this lane's slot
    const u16* const baseA = A  + (size_t)(m0 + w * 16 + lrow) * K + lc * 8;
    const u16* const baseB = BT + (size_t)(n0 + w * 16 + lrow) * K + lc * 8;
    const int wdst = w * 1024;                // wave's 2KB (u16 units) in a half

    // ---- ds_read geometry (swizzled chunks) ----
    const int pc0  = (quad ^ (fr & 7)) * 8;
    const int pc1  = pc0 ^ 32;                // (chunk^4)*8
    const int aRow = (wm * 64 + fr) * 64;
    const int bRow = (wn * 32 + fr) * 64;

    f32x4 acc[2][2][4][2];
#pragma unroll
    for (int a = 0; a < 2; ++a)
#pragma unroll
        for (int b = 0; b < 2; ++b)
#pragma unroll
            for (int c = 0; c < 4; ++c)
#pragma unroll
                for (int d = 0; d < 2; ++d) acc[a][b][c][d] = (f32x4)0.f;

    short8 ar0[4][2], ar1[4][2], br[2][2];

    auto stA = [&](int off, int tile, int mh) {
        const u16* g = baseA + (size_t)mh * 128 * K + tile * 64;
        glds16(g,                 smem + off + wdst);
        glds16(g + (size_t)8 * K, smem + off + wdst + 512);
    };
    auto stB = [&](int off, int tile, int nh) {
        const u16* g = baseB + (size_t)nh * 128 * K + tile * 64;
        glds16(g,                 smem + off + wdst);
        glds16(g + (size_t)8 * K, smem + off + wdst + 512);
    };
    auto rdA = [&](short8 (&d)[4][2], int off) {
#pragma unroll
        for (int mr = 0; mr < 4; ++mr) {
            d[mr][0] = *(const short8*)&smem[off + aRow + mr * 1024 + pc0];
            d[mr][1] = *(const short8*)&smem[off + aRow + mr * 1024 + pc1];
        }
    };
    auto rdB = [&](short8 (&d)[2][2], int off) {
#pragma unroll
        for (int nc = 0; nc < 2; ++nc) {
            d[nc][0] = *(const short8*)&smem[off + bRow + nc * 1024 + pc0];
            d[nc][1] = *(const short8*)&smem[off + bRow + nc * 1024 + pc1];
        }
    };
    auto mma = [&](short8 (&a)[4][2], short8 (&b)[2][2], f32x4 (&c)[4][2]) {
        __builtin_amdgcn_s_setprio(1);
#pragma unroll
        for (int mr = 0; mr < 4; ++mr)
#pragma unroll
            for (int nc = 0; nc < 2; ++nc) {
                c[mr][nc] = __builtin_amdgcn_mfma_f32_16x16x32_bf16(a[mr][0], b[nc][0], c[mr][nc], 0, 0, 0);
                c[mr][nc] = __builtin_amdgcn_mfma_f32_16x16x32_bf16(a[mr][1], b[nc][1], c[mr][nc], 0, 0, 0);
            }
        __builtin_amdgcn_s_setprio(0);
    };

    // ---- prologue: tile0 fully + tile1 {A0,B0,A1}; B1(t1) comes in phase 1 ----
    stA(AOFFU(0,0), 0, 0);
    stB(BOFFU(0,0), 0, 0);
    stA(AOFFU(0,1), 0, 1);
    stB(BOFFU(0,1), 0, 1);
    stA(AOFFU(1,0), 1, 0);
    stB(BOFFU(1,0), 1, 0);
    stA(AOFFU(1,1), 1, 1);
    asm volatile("s_waitcnt vmcnt(6)" ::: "memory");   // tile0 landed
    __builtin_amdgcn_s_barrier();

    for (int T = 0; T < NT; T += 2) {
        const int ts2 = (T + 2 < NT) ? T + 2 : NT - 1;   // clamped (dead-slot writes)
        const int ts3 = (T + 3 < NT) ? T + 3 : NT - 1;
        // ---- phase 1: quad (0,0) of tile T (par0); stage S(T+1,B1) ----
        rdA(ar0, AOFFU(0,0));
        rdB(br,  BOFFU(0,0));
        stB(BOFFU(1,1), T + 1, 1);
        __builtin_amdgcn_s_barrier();
        asm volatile("s_waitcnt lgkmcnt(0)" ::: "memory");
        mma(ar0, br, acc[0][0]);
        __builtin_amdgcn_s_barrier();
        // ---- phase 2: (1,0); stage S(T+2,A0) ----
        rdA(ar1, AOFFU(0,1));
        stA(AOFFU(0,0), ts2, 0);
        __builtin_amdgcn_s_barrier();
        asm volatile("s_waitcnt lgkmcnt(0)" ::: "memory");
        mma(ar1, br, acc[1][0]);
        __builtin_amdgcn_s_barrier();
        // ---- phase 3: (1,1); stage S(T+2,B0) ----
        rdB(br, BOFFU(0,1));
        stB(BOFFU(0,0), ts2, 0);
        __builtin_amdgcn_s_barrier();
        asm volatile("s_waitcnt lgkmcnt(0)" ::: "memory");
        mma(ar1, br, acc[1][1]);
        __builtin_amdgcn_s_barrier();
        // ---- phase 4: (0,1) (regs only); stage S(T+2,A1); vmcnt(6) -> T+1 ready ----
        stA(AOFFU(0,1), ts2, 1);
        __builtin_amdgcn_s_barrier();
        asm volatile("s_waitcnt lgkmcnt(0)" ::: "memory");
        mma(ar0, br, acc[0][1]);
        asm volatile("s_waitcnt vmcnt(6)" ::: "memory");
        __builtin_amdgcn_s_barrier();
        // ---- phase 5: (0,0) of tile T+1 (par1); stage S(T+2,B1) ----
        rdA(ar0, AOFFU(1,0));
        rdB(br,  BOFFU(1,0));
        stB(BOFFU(0,1), ts2, 1);
        __builtin_amdgcn_s_barrier();
        asm volatile("s_waitcnt lgkmcnt(0)" ::: "memory");
        mma(ar0, br, acc[0][0]);
        __builtin_amdgcn_s_barrier();
        // ---- phase 6: (1,0); stage S(T+3,A0) ----
        rdA(ar1, AOFFU(1,1));
        stA(AOFFU(1,0), ts3, 0);
        __builtin_amdgcn_s_barrier();
        asm volatile("s_waitcnt lgkmcnt(0)" ::: "memory");
        mma(ar1, br, acc[1][0]);
        __builtin_amdgcn_s_barrier();
        // ---- phase 7: (1,1); stage S(T+3,B0) ----
        rdB(br, BOFFU(1,1));
        stB(BOFFU(1,0), ts3, 0);
        __builtin_amdgcn_s_barrier();
        asm volatile("s_waitcnt lgkmcnt(0)" ::: "memory");
        mma(ar1, br, acc[1][1]);
        __builtin_amdgcn_s_barrier();
        // ---- phase 8: (0,1) (regs only); stage S(T+3,A1); vmcnt(6) -> T+2 ready ----
        stA(AOFFU(1,1), ts3, 1);
        __builtin_amdgcn_s_barrier();
        asm volatile("s_waitcnt lgkmcnt(0)" ::: "memory");
        mma(ar0, br, acc[0][1]);
        asm volatile("s_waitcnt vmcnt(6)" ::: "memory");
        __builtin_amdgcn_s_barrier();
    }

    // ---- epilogue: region select + C write (bf16) ----
    u16* dst; int stride, nbase;
    if (n0 < DQ)            { dst = qb; stride = DQ;  nbase = n0; }
    else if (n0 < DQ + DKV) { dst = kb; stride = DKV; nbase = n0 - DQ; }
    else                    { dst = vb; stride = DKV; nbase = n0 - DQ - DKV; }

    const int col = lane & 15;
    const int rq  = (lane >> 4) * 4;
#pragma unroll
    for (int mh = 0; mh < 2; ++mh)
#pragma unroll
        for (int nh = 0; nh < 2; ++nh)
#pragma unroll
            for (int mr = 0; mr < 4; ++mr)
#pragma unroll
                for (int nc = 0; nc < 2; ++nc)
#pragma unroll
                    for (int i = 0; i < 4; ++i)
                        dst[(size_t)(m0 + mh * 128 + wm * 64 + mr * 16 + rq + i) * stride
                            + nbase + nh * 128 + wn * 32 + nc * 16 + col] =
                            bf16_rne(acc[mh][nh][mr][nc][i]);
}

// ---------------------------------------------------------------------------
// O-projection GEMM: BM=128 x BN=256, BK=64, full K, 8-phase quadrant schedule.
// Grid 16x16 = 256 blocks = full machine, one round. No split-K, no reduction.
// LDS 96 KiB: A[2par][128][64] + B[2par][2half][128][64]. 8 waves (2M x 4N),
// per-wave C = 64x64 (4x4 frags) processed as 2x2 quadrants of 8 MFMA.
// Stage ops per K-tile: {A, B0, B1}. Slot lifetimes: A reads end ph2 -> stA@ph3;
// B half reads end ph3 (qn0@ph1, qn1@ph3) -> stB x2 @ph4. vmcnt(6) at ph4/ph8
// with exactly the next tile's 3 stages (6 loads) in flight.
// ---------------------------------------------------------------------------
#define OAOFF(par)     ((par) * 8192)
#define OBOFF(par, nh) (16384 + (par) * 16384 + (nh) * 8192)

__global__ __launch_bounds__(512, 2) void gemm_o128(const u16* __restrict__ A,
                                                    const u16* __restrict__ BT,
                                                    float* __restrict__ C) {
    const int LDA = DQ;      // K = 4096, row stride of A (aob) and BT (woT)
    const int NT  = 64;
    __shared__ u16 smem[49152] __attribute__((aligned(16)));

    const int t    = threadIdx.x;
    const int w    = t >> 6;        // 0..7
    const int lane = t & 63;
    const int wm   = w >> 2;        // 0..1 (M)
    const int wn   = w & 3;         // 0..3 (N)
    const int fr   = lane & 15;
    const int quad = lane >> 4;
    const int m0   = blockIdx.y * 128;
    const int n0   = blockIdx.x * 256;
    const int bh   = wn >> 1;       // which B half this wave reads

    const int lrow = lane >> 3;
    const int lc   = (lane & 7) ^ lrow;
    const u16* const baseA = A  + (size_t)(m0 + w * 16 + lrow) * LDA + lc * 8;
    const u16* const baseB = BT + (size_t)(n0 + w * 16 + lrow) * LDA + lc * 8;
    const int wdst = w * 1024;

    const int pc0  = (quad ^ (fr & 7)) * 8;
    const int pc1  = pc0 ^ 32;
    const int aRow = (wm * 64 + fr) * 64;          // + mr*1024
    const int bRow = ((wn & 1) * 64 + fr) * 64;    // + nc*1024 (within half bh)

    f32x4 acc[4][4];
#pragma unroll
    for (int i = 0; i < 4; ++i)
#pragma unroll
        for (int j = 0; j < 4; ++j) acc[i][j] = (f32x4)0.f;

    short8 a0[2][2], a1[2][2], b[2][2];

    auto stA = [&](int off, int tile) {
        const u16* g = baseA + tile * 64;
        glds16(g,                   smem + off + wdst);
        glds16(g + (size_t)8 * LDA, smem + off + wdst + 512);
    };
    auto stB = [&](int off, int tile, int nh) {
        const u16* g = baseB + (size_t)nh * 128 * LDA + tile * 64;
        glds16(g,                   smem + off + wdst);
        glds16(g + (size_t)8 * LDA, smem + off + wdst + 512);
    };
    auto rdA2 = [&](short8 (&d)[2][2], int off, int qm) {
#pragma unroll
        for (int m2 = 0; m2 < 2; ++m2) {
            d[m2][0] = *(const short8*)&smem[off + aRow + (2 * qm + m2) * 1024 + pc0];
            d[m2][1] = *(const short8*)&smem[off + aRow + (2 * qm + m2) * 1024 + pc1];
        }
    };
    auto rdB2 = [&](short8 (&d)[2][2], int off, int qn) {
#pragma unroll
        for (int n2 = 0; n2 < 2; ++n2) {
            d[n2][0] = *(const short8*)&smem[off + bRow + (2 * qn + n2) * 1024 + pc0];
            d[n2][1] = *(const short8*)&smem[off + bRow + (2 * qn + n2) * 1024 + pc1];
        }
    };
    auto mma8 = [&](short8 (&a)[2][2], short8 (&bb)[2][2], int qm, int qn) {
        __builtin_amdgcn_s_setprio(1);
#pragma unroll
        for (int m2 = 0; m2 < 2; ++m2)
#pragma unroll
            for (int n2 = 0; n2 < 2; ++n2) {
                acc[2 * qm + m2][2 * qn + n2] = __builtin_amdgcn_mfma_f32_16x16x32_bf16(
                    a[m2][0], bb[n2][0], acc[2 * qm + m2][2 * qn + n2], 0, 0, 0);
                acc[2 * qm + m2][2 * qn + n2] = __builtin_amdgcn_mfma_f32_16x16x32_bf16(
                    a[m2][1], bb[n2][1], acc[2 * qm + m2][2 * qn + n2], 0, 0, 0);
            }
        __builtin_amdgcn_s_setprio(0);
    };

    // ---- prologue: stage tiles 0 and 1 fully (6 ops = 12 loads) ----
    stA(OAOFF(0), 0);
    stB(OBOFF(0,0), 0, 0);
    stB(OBOFF(0,1), 0, 1);
    stA(OAOFF(1), 1);
    stB(OBOFF(1,0), 1, 0);
    stB(OBOFF(1,1), 1, 1);
    asm volatile("s_waitcnt vmcnt(6)" ::: "memory");   // tile0 landed
    __builtin_amdgcn_s_barrier();

    for (int T = 0; T < NT; T += 2) {
        const int ts2 = (T + 2 < NT) ? T + 2 : NT - 1;   // clamped (dead-slot writes)
        const int ts3 = (T + 3 < NT) ? T + 3 : NT - 1;
        // ---- phase 1: quadrant (0,0) of tile T (par0) ----
        rdA2(a0, OAOFF(0), 0);
        rdB2(b,  OBOFF(0, bh), 0);
        __builtin_amdgcn_s_barrier();
        asm volatile("s_waitcnt lgkmcnt(0)" ::: "memory");
        mma8(a0, b, 0, 0);
        __builtin_amdgcn_s_barrier();
        // ---- phase 2: (1,0) ----
        rdA2(a1, OAOFF(0), 1);
        __builtin_amdgcn_s_barrier();
        asm volatile("s_waitcnt lgkmcnt(0)" ::: "memory");
        mma8(a1, b, 1, 0);
        __builtin_amdgcn_s_barrier();
        // ---- phase 3: (1,1); stage S(T+2,A) [A-par0 reads done ph1,ph2] ----
        rdB2(b, OBOFF(0, bh), 1);
        stA(OAOFF(0), ts2);
        __builtin_amdgcn_s_barrier();
        asm volatile("s_waitcnt lgkmcnt(0)" ::: "memory");
        mma8(a1, b, 1, 1);
        __builtin_amdgcn_s_barrier();
        // ---- phase 4: (0,1) regs only; stage S(T+2,B0),S(T+2,B1); vmcnt(6)->T+1 ready ----
        stB(OBOFF(0,0), ts2, 0);
        stB(OBOFF(0,1), ts2, 1);
        __builtin_amdgcn_s_barrier();
        asm volatile("s_waitcnt lgkmcnt(0)" ::: "memory");
        mma8(a0, b, 0, 1);
        asm volatile("s_waitcnt vmcnt(6)" ::: "memory");
        __builtin_amdgcn_s_barrier();
        // ---- phase 5: (0,0) of tile T+1 (par1) ----
        rdA2(a0, OAOFF(1), 0);
        rdB2(b,  OBOFF(1, bh), 0);
        __builtin_amdgcn_s_barrier();
        asm volatile("s_waitcnt lgkmcnt(0)" ::: "memory");
        mma8(a0, b, 0, 0);
        __builtin_amdgcn_s_barrier();
        // ---- phase 6: (1,0) ----
        rdA2(a1, OAOFF(1), 1);
        __builtin_amdgcn_s_barrier();
        asm volatile("s_waitcnt lgkmcnt(0)" ::: "memory");
        mma8(a1, b, 1, 0);
        __builtin_amdgcn_s_barrier();
        // ---- phase 7: (1,1); stage S(T+3,A) ----
        rdB2(b, OBOFF(1, bh), 1);
        stA(OAOFF(1), ts3);
        __builtin_amdgcn_s_barrier();
        asm volatile("s_waitcnt lgkmcnt(0)" ::: "memory");
        mma8(a1, b, 1, 1);
        __builtin_amdgcn_s_barrier();
        // ---- phase 8: (0,1) regs only; stage S(T+3,B0),S(T+3,B1); vmcnt(6)->T+2 ready ----
        stB(OBOFF(1,0), ts3, 0);
        stB(OBOFF(1,1), ts3, 1);
        __builtin_amdgcn_s_barrier();
        asm volatile("s_waitcnt lgkmcnt(0)" ::: "memory");
        mma8(a0, b, 0, 1);
        asm volatile("s_waitcnt vmcnt(6)" ::: "memory");
        __builtin_amdgcn_s_barrier();
    }

    // ---- epilogue: fp32 C write ----
    const int col = lane & 15;
    const int rq  = (lane >> 4) * 4;
#pragma unroll
    for (int mr = 0; mr < 4; ++mr)
#pragma unroll
        for (int nc = 0; nc < 4; ++nc)
#pragma unroll
            for (int i = 0; i < 4; ++i)
                C[(size_t)(m0 + wm * 64 + mr * 16 + rq + i) * HDIM
                  + n0 + wn * 64 + nc * 16 + col] = acc[mr][nc][i];
}

// ---------------------------------------------------------------------------
// Merged RoPE (blocks [0,5120)) + V transpose (blocks [5120, 5632)).
// ---------------------------------------------------------------------------
__global__ __launch_bounds__(256) void rope_tv(u16* __restrict__ q, u16* __restrict__ k,
                                               const float* __restrict__ cosT,
                                               const float* __restrict__ sinT,
                                               const u16* __restrict__ V,
                                               u16* __restrict__ Vt) {
    __shared__ u16 tile[64][72];
    const int bid = blockIdx.x;
    const int t = threadIdx.x;
    if (bid < 5120) {
        int idx = bid * 256 + t;                      // S * 40 * 16
        int d4   = (idx & 15) * 4;                    // 0..60
        int rest = idx >> 4;
        int head = rest % (NQ_H + NKV_H);
        int s    = rest / (NQ_H + NKV_H);
        u16* base = (head < NQ_H)
            ? q + ((size_t)s * NQ_H + head) * HD_
            : k + ((size_t)s * NKV_H + (head - NQ_H)) * HD_;
        float4 c  = *(const float4*)&cosT[s * HD_ + d4];
        float4 sn = *(const float4*)&sinT[s * HD_ + d4];
        u16 lo[4], hi[4];
        *(uint2*)lo = *(uint2*)&base[d4];
        *(uint2*)hi = *(uint2*)&base[d4 + 64];
        float cs[4] = {c.x, c.y, c.z, c.w};
        float ss[4] = {sn.x, sn.y, sn.z, sn.w};
        u16 nlo[4], nhi[4];
#pragma unroll
        for (int j = 0; j < 4; ++j) {
            float x1 = bf16_to_f(lo[j]);
            float x2 = bf16_to_f(hi[j]);
            nlo[j] = bf16_rne(x1 * cs[j] - x2 * ss[j]);
            nhi[j] = bf16_rne(x2 * cs[j] + x1 * ss[j]);
        }
        *(uint2*)&base[d4]      = *(uint2*)nlo;
        *(uint2*)&base[d4 + 64] = *(uint2*)nhi;
        return;
    }
    const int b   = bid - 5120;        // 0..511
    const int s0  = (b & 31) * 64;
    const int yy  = b >> 5;            // 0..15
    const int kvh = yy >> 1;
    const int d0  = (yy & 1) * 64;
    const int chunk = t & 7;       // 8 x 16B per 64-wide row
    const int row   = t >> 3;      // 0..31
#pragma unroll
    for (int p = 0; p < 2; ++p) {
        int s = row + 32 * p;
        uint4 x = *(const uint4*)&V[(size_t)(s0 + s) * DKV + kvh * HD_ + d0 + chunk * 8];
        *(uint4*)&tile[s][chunk * 8] = x;
    }
    __syncthreads();
#pragma unroll
    for (int p = 0; p < 2; ++p) {
        int d = row + 32 * p;
        u16 tmp[8];
#pragma unroll
        for (int j = 0; j < 8; ++j) tmp[j] = tile[chunk * 8 + j][d];
        *(uint4*)&Vt[(size_t)(kvh * HD_ + d0 + d) * S_LEN + s0 + chunk * 8] = *(uint4*)tmp;
    }
}

// ---------------------------------------------------------------------------
// MFMA flash attention, causal GQA, fixed-base softmax (exact after o/l).
// Block = (128 q-rows, head); 8 waves x 16 q-rows; KV tile 64.
// T14 reg-prefetch of next K/V tile; XOR-swizzled unpadded sK/sVt; T5 setprio.
// ---------------------------------------------------------------------------
#define QSTR 136
#define PSTR 76
__global__ __launch_bounds__(512, 4) void attn_mfma(const u16* __restrict__ Q,
                                                    const u16* __restrict__ K,
                                                    const u16* __restrict__ Vt,
                                                    u16* __restrict__ O) {
    __shared__ u16 smem[26112] __attribute__((aligned(16)));
    u16* sK  = smem;            // [64][128] swizzled : 8192 u16
    u16* sVt = smem + 8192;     // [128][64] swizzled : 8192 u16
    u16* sP  = smem + 16384;    // 8 x [16][PSTR]     : 9728 u16
    u16* sQ  = sVt;             // union (sQ only live pre-loop)

    const int id  = blockIdx.x;
    const int h   = id & 31;
    const int qt  = (id < 256) ? (15 - (id >> 5)) : ((id - 256) >> 5);
    const int kvh = h >> 2;
    const int q0  = qt * 128;
    const int t    = threadIdx.x;
    const int w    = t >> 6;        // 0..7
    const int lane = t & 63;
    const int fr   = lane & 15;
    const int quad = lane >> 4;
    const int nkt  = 2 * qt + 2;

    const float K1 = 0.12751744154f;   // (1/sqrt(128)) * log2(e)
    const float K2 = 11.5415603267f;   // 8 * log2(e)

    const int kRow  = t >> 3;                             // 0..63
    const int kC    = t & 7;                              // 2 chunks of 16B
    const int kLds0 = kRow * 128 + (((2 * kC + 0) ^ (kRow & 7)) * 8);
    const int kLds1 = kRow * 128 + (((2 * kC + 1) ^ (kRow & 7)) * 8);
    const u16* const kGp = K + (size_t)kRow * DKV + (size_t)kvh * HD_ + kC * 16;

    const int vRow  = t >> 2;                             // 0..127
    const int vC    = t & 3;
    const int vLds0 = vRow * 64 + (((2 * vC + 0) ^ (vRow & 7)) * 8);
    const int vLds1 = vRow * 64 + (((2 * vC + 1) ^ (vRow & 7)) * 8);
    const u16* const vGp = Vt + ((size_t)kvh * HD_ + vRow) * S_LEN + vC * 16;

    uint4 kr0 = *(const uint4*)(kGp);
    uint4 kr1 = *(const uint4*)(kGp + 8);
    uint4 vr0 = *(const uint4*)(vGp);
    uint4 vr1 = *(const uint4*)(vGp + 8);

    {
        const int col  = t & 15;
        const int row4 = t >> 4;    // 32 rows per pass
#pragma unroll
        for (int p = 0; p < 4; ++p) {
            int row = row4 + 32 * p;
            uint4 xv = *(const uint4*)&Q[(size_t)(q0 + row) * DQ + h * HD_ + col * 8];
            *(uint4*)&sQ[row * QSTR + col * 8] = xv;
        }
    }
    __syncthreads();

    short8 aq[4];
#pragma unroll
    for (int ks = 0; ks < 4; ++ks)
        aq[ks] = *(const short8*)&sQ[(16 * w + fr) * QSTR + ks * 32 + quad * 8];

    float lrow[4] = {0.f, 0.f, 0.f, 0.f};
    f32x4 oacc[8];
#pragma unroll
    for (int n8 = 0; n8 < 8; ++n8) oacc[n8] = (f32x4)0.f;

    u16* const sPw   = sP + w * (16 * PSTR);
    const int  qwTop = q0 + 16 * w;     // wave's first q row

    for (int kt = 0; kt < nkt; ++kt) {
        const int k0 = kt * 64;
        __syncthreads();

        *(uint4*)&sK[kLds0]  = kr0;
        *(uint4*)&sK[kLds1]  = kr1;
        *(uint4*)&sVt[vLds0] = vr0;
        *(uint4*)&sVt[vLds1] = vr1;
        if (kt + 1 < nkt) {
            const u16* kp = kGp + (size_t)(k0 + 64) * DKV;
            kr0 = *(const uint4*)(kp);
            kr1 = *(const uint4*)(kp + 8);
            const u16* vp = vGp + (k0 + 64);
            vr0 = *(const uint4*)(vp);
            vr1 = *(const uint4*)(vp + 8);
        }
        __syncthreads();

        if (k0 <= qwTop + 15) {
            f32x4 sacc[4];
#pragma unroll
            for (int nt = 0; nt < 4; ++nt) sacc[nt] = (f32x4)0.f;
            __builtin_amdgcn_s_setprio(1);
#pragma unroll
            for (int ks = 0; ks < 4; ++ks)
#pragma unroll
                for (int nt = 0; nt < 4; ++nt) {
                    const short8 bk = *(const short8*)
                        &sK[(nt * 16 + fr) * 128 + (((ks * 4 + quad) ^ (fr & 7)) * 8)];
                    sacc[nt] = __builtin_amdgcn_mfma_f32_16x16x32_bf16(aq[ks], bk, sacc[nt], 0, 0, 0);
                }
            __builtin_amdgcn_s_setprio(0);

            if (k0 + 63 > qwTop) {
#pragma unroll
                for (int nt = 0; nt < 4; ++nt) {
                    int key = k0 + nt * 16 + fr;
#pragma unroll
                    for (int i = 0; i < 4; ++i)
                        if (key > qwTop + quad * 4 + i) sacc[nt][i] = -INFINITY;
                }
            }

#pragma unroll
            for (int nt = 0; nt < 4; ++nt)
#pragma unroll
                for (int i = 0; i < 4; ++i) {
                    float p = __builtin_amdgcn_exp2f(fmaf(sacc[nt][i], K1, -K2));
                    lrow[i] += p;
                    sPw[(quad * 4 + i) * PSTR + nt * 16 + fr] = bf16_rne(p);
                }

            __builtin_amdgcn_s_setprio(1);
#pragma unroll
            for (int ks2 = 0; ks2 < 2; ++ks2) {
                const short8 ap = *(const short8*)&sPw[fr * PSTR + ks2 * 32 + quad * 8];
#pragma unroll
                for (int n8 = 0; n8 < 8; ++n8) {
                    const short8 bv = *(const short8*)
                        &sVt[(n8 * 16 + fr) * 64 + (((ks2 * 4 + quad) ^ (fr & 7)) * 8)];
                    oacc[n8] = __builtin_amdgcn_mfma_f32_16x16x32_bf16(ap, bv, oacc[n8], 0, 0, 0);
                }
            }
            __builtin_amdgcn_s_setprio(0);
        }
    }

#pragma unroll
    for (int i = 0; i < 4; ++i) {
        lrow[i] += __shfl_xor(lrow[i], 1);
        lrow[i] += __shfl_xor(lrow[i], 2);
        lrow[i] += __shfl_xor(lrow[i], 4);
        lrow[i] += __shfl_xor(lrow[i], 8);
    }
#pragma unroll
    for (int i = 0; i < 4; ++i) {
        float inv = 1.f / lrow[i];
        size_t base = (size_t)(qwTop + quad * 4 + i) * DQ + h * HD_;
#pragma unroll
        for (int n8 = 0; n8 < 8; ++n8)
            O[base + n8 * 16 + fr] = bf16_rne(oacc[n8][i] * inv);
    }
}

// ---------------------------------------------------------------------------
extern "C" void kernel_launch(void* const* d_in, const int* in_sizes, int n_in,
                              void* d_out, int out_size, void* d_ws, size_t ws_size,
                              hipStream_t stream) {
    const float* X    = (const float*)d_in[0];
    const float* cosT = (const float*)d_in[1];
    const float* sinT = (const float*)d_in[2];
    const float* wq   = (const float*)d_in[3];
    const float* wk   = (const float*)d_in[4];
    const float* wv   = (const float*)d_in[5];
    const float* wo   = (const float*)d_in[6];
    float* out = (float*)d_out;

    const size_t SDQ  = (size_t)S_LEN * DQ;    // 8.4M
    const size_t SDKV = (size_t)S_LEN * DKV;   // 2.1M
    const size_t WQKV = (size_t)HDIM * NFUSE;  // 25.2M

    // ws layout (u16), ~147 MB
    u16* Xb  = (u16*)d_ws;
    u16* qb  = Xb + SDQ;
    u16* kb  = qb + SDQ;
    u16* vb  = kb + SDKV;
    u16* vtb = vb + SDKV;
    u16* aob = vtb + SDKV;
    u16* WT  = aob + SDQ;      // fused qkv weights, 6144 x 4096
    u16* woT = WT + WQKV;

    dim3 blk(256);

    // merged conversions: X->Xb (4096 blocks) + [wq|wk|wv]->WT (24576 blocks)
    cvt_all<<<dim3(4096 + 24576), blk, 0, stream>>>(X, Xb, wq, wk, wv, WT);

    // fused QKV projection (192 GEMM blocks) + wo transpose on 64 filler blocks
    gemm_qkv256<<<dim3(256), dim3(512), 0, stream>>>(Xb, WT, qb, kb, vb, wo, woT);

    // merged rope (5120 blocks) + V pre-transpose (512 blocks)
    rope_tv<<<dim3(5120 + 512), blk, 0, stream>>>(qb, kb, cosT, sinT, vb, vtb);

    // attention: 512 blocks (16 q-tiles x 32 heads), 512 threads
    attn_mfma<<<dim3(512), dim3(512), 0, stream>>>(qb, kb, vtb, aob);

    // output projection: 128x256 tiles, full K, 256 blocks = 1 full round
    gemm_o128<<<dim3(HDIM / 256, S_LEN / 128), dim3(512), 0, stream>>>(aob, woT, out);
}